// Round 1
// baseline (1203.003 us; speedup 1.0000x reference)
//
#include <hip/hip_runtime.h>
#include <hip/hip_bf16.h>
#include <math.h>

// TreeLSTM: L=16384, D=256, 5 gates (i, fl, fr, o, u), 15 levels, then proj to 5.
// ws layout: h_all[32767*256] f32, then c_all[32767*256] f32  (~67 MB total).

#define TM 8

__device__ __forceinline__ float sigf(float x) { return 1.0f / (1.0f + __expf(-x)); }

// ---------------- Level 0: pre = emb[tokens] @ Wx + b; cell with c_l=c_r=0 ----
__global__ __launch_bounds__(256) void lvl0_kernel(
    const int* __restrict__ tokens, const float* __restrict__ emb,
    const float* __restrict__ Wx, const float* __restrict__ b,
    float* __restrict__ h_out, float* __restrict__ c_out)
{
    __shared__ __align__(16) float xs[TM][256];
    const int d = threadIdx.x;            // output column within a gate, 0..255
    const int row0 = blockIdx.x * TM;

    #pragma unroll
    for (int m = 0; m < TM; ++m) {
        int r = row0 + m;                 // 16384 % TM == 0 -> no guard
        int tok = tokens[r];
        xs[m][d] = emb[(size_t)tok * 256 + d];
    }
    __syncthreads();

    float bg[5];
    #pragma unroll
    for (int g = 0; g < 5; ++g) bg[g] = b[g * 256 + d];

    float acc[TM][5];
    #pragma unroll
    for (int m = 0; m < TM; ++m)
        #pragma unroll
        for (int g = 0; g < 5; ++g) acc[m][g] = 0.f;

    for (int k = 0; k < 256; k += 4) {
        float w[4][5];
        #pragma unroll
        for (int kk = 0; kk < 4; ++kk)
            #pragma unroll
            for (int g = 0; g < 5; ++g)
                w[kk][g] = Wx[(size_t)(k + kk) * 1280 + g * 256 + d];
        #pragma unroll
        for (int m = 0; m < TM; ++m) {
            float4 xv = *(const float4*)&xs[m][k];
            #pragma unroll
            for (int g = 0; g < 5; ++g)
                acc[m][g] = fmaf(xv.w, w[3][g],
                            fmaf(xv.z, w[2][g],
                            fmaf(xv.y, w[1][g],
                            fmaf(xv.x, w[0][g], acc[m][g]))));
        }
    }

    #pragma unroll
    for (int m = 0; m < TM; ++m) {
        int r = row0 + m;
        float gi = acc[m][0] + bg[0];
        float go = acc[m][3] + bg[3];
        float gu = acc[m][4] + bg[4];
        float cc = sigf(gi) * tanhf(gu);          // c_l = c_r = 0
        float hh = sigf(go) * tanhf(cc);
        h_out[(size_t)r * 256 + d] = hh;
        c_out[(size_t)r * 256 + d] = cc;
    }
}

// ------------- Levels 1..14: pre = hl@Ul + hr@Ur + b; cell(cl, cr) -----------
// h_prev rows (2p, 2p+1) are contiguous -> treat h_prev as (n, 512), K=512 GEMM
// with stacked weights [Ul; Ur].
__global__ __launch_bounds__(256) void lvl_kernel(
    const float* __restrict__ hp, const float* __restrict__ cp,
    const float* __restrict__ Ul, const float* __restrict__ Ur,
    const float* __restrict__ b,
    float* __restrict__ h_out, float* __restrict__ c_out, int n)
{
    __shared__ __align__(16) float xs[TM][512];
    const int d = threadIdx.x;
    const int row0 = blockIdx.x * TM;

    #pragma unroll
    for (int m = 0; m < TM; ++m) {
        int r = row0 + m;
        if (r < n) {
            const float* src = hp + (size_t)r * 512;
            xs[m][d]       = src[d];
            xs[m][d + 256] = src[d + 256];
        } else {
            xs[m][d] = 0.f;
            xs[m][d + 256] = 0.f;
        }
    }
    __syncthreads();

    float bg[5];
    #pragma unroll
    for (int g = 0; g < 5; ++g) bg[g] = b[g * 256 + d];

    float acc[TM][5];
    #pragma unroll
    for (int m = 0; m < TM; ++m)
        #pragma unroll
        for (int g = 0; g < 5; ++g) acc[m][g] = 0.f;

    #pragma unroll
    for (int half = 0; half < 2; ++half) {
        const float* __restrict__ Wb = half ? Ur : Ul;
        const int kb = half * 256;
        for (int k = 0; k < 256; k += 4) {
            float w[4][5];
            #pragma unroll
            for (int kk = 0; kk < 4; ++kk)
                #pragma unroll
                for (int g = 0; g < 5; ++g)
                    w[kk][g] = Wb[(size_t)(k + kk) * 1280 + g * 256 + d];
            #pragma unroll
            for (int m = 0; m < TM; ++m) {
                float4 xv = *(const float4*)&xs[m][kb + k];
                #pragma unroll
                for (int g = 0; g < 5; ++g)
                    acc[m][g] = fmaf(xv.w, w[3][g],
                                fmaf(xv.z, w[2][g],
                                fmaf(xv.y, w[1][g],
                                fmaf(xv.x, w[0][g], acc[m][g]))));
            }
        }
    }

    #pragma unroll
    for (int m = 0; m < TM; ++m) {
        int r = row0 + m;
        if (r < n) {
            float gi = acc[m][0] + bg[0];
            float gl = acc[m][1] + bg[1];
            float gr = acc[m][2] + bg[2];
            float go = acc[m][3] + bg[3];
            float gu = acc[m][4] + bg[4];
            float cl = cp[(size_t)(2 * r) * 256 + d];
            float cr = cp[(size_t)(2 * r + 1) * 256 + d];
            float cc = sigf(gi) * tanhf(gu) + sigf(gl) * cl + sigf(gr) * cr;
            float hh = sigf(go) * tanhf(cc);
            h_out[(size_t)r * 256 + d] = hh;
            c_out[(size_t)r * 256 + d] = cc;
        }
    }
}

// ---------------- Projection: out = hidden @ Wp + bp  (32767 x 5) ------------
__global__ __launch_bounds__(256) void proj_kernel(
    const float* __restrict__ h, const float* __restrict__ Wp,
    const float* __restrict__ bp, float* __restrict__ out, int n)
{
    const int wave = blockIdx.x * 4 + (threadIdx.x >> 6);
    const int lane = threadIdx.x & 63;
    if (wave >= n) return;

    const float* hr = h + (size_t)wave * 256;
    float s[5] = {0.f, 0.f, 0.f, 0.f, 0.f};
    #pragma unroll
    for (int q = 0; q < 4; ++q) {
        int dd = lane + 64 * q;
        float hv = hr[dd];
        #pragma unroll
        for (int j = 0; j < 5; ++j) s[j] += hv * Wp[dd * 5 + j];
    }
    #pragma unroll
    for (int off = 32; off; off >>= 1)
        #pragma unroll
        for (int j = 0; j < 5; ++j) s[j] += __shfl_down(s[j], off);

    if (lane == 0) {
        #pragma unroll
        for (int j = 0; j < 5; ++j) out[(size_t)wave * 5 + j] = s[j] + bp[j];
    }
}

extern "C" void kernel_launch(void* const* d_in, const int* in_sizes, int n_in,
                              void* d_out, int out_size, void* d_ws, size_t ws_size,
                              hipStream_t stream)
{
    const int*   tokens = (const int*)  d_in[0];
    const float* emb    = (const float*)d_in[1];
    const float* Wx     = (const float*)d_in[2];
    const float* Ul     = (const float*)d_in[3];
    const float* Ur     = (const float*)d_in[4];
    const float* b      = (const float*)d_in[5];
    const float* Wp     = (const float*)d_in[6];
    const float* bp     = (const float*)d_in[7];
    float* out = (float*)d_out;

    float* h_all = (float*)d_ws;
    float* c_all = h_all + (size_t)32767 * 256;

    int off[16];
    off[0] = 0;
    for (int t = 0; t < 15; ++t) off[t + 1] = off[t] + (16384 >> t);

    lvl0_kernel<<<16384 / TM, 256, 0, stream>>>(tokens, emb, Wx, b, h_all, c_all);

    for (int t = 1; t <= 14; ++t) {
        int n    = 16384 >> t;
        int prev = off[t - 1];
        int cur  = off[t];
        int grid = (n + TM - 1) / TM;
        lvl_kernel<<<grid, 256, 0, stream>>>(
            h_all + (size_t)prev * 256, c_all + (size_t)prev * 256,
            Ul, Ur, b,
            h_all + (size_t)cur * 256, c_all + (size_t)cur * 256, n);
    }

    int total = off[15];  // 32767
    proj_kernel<<<(total + 3) / 4, 256, 0, stream>>>(h_all, Wp, bp, out, total);
}

// Round 2
// 413.552 us; speedup vs baseline: 2.9090x; 2.9090x over previous
//
#include <hip/hip_runtime.h>
#include <hip/hip_bf16.h>
#include <math.h>
#include <stdint.h>

// TreeLSTM on MFMA: L=16384, D=256, 5 gates, 15 levels, proj to 5.
// Split-precision bf16 (hi+lo) GEMMs: A*B ~= Ahi*Bhi + Alo*Bhi + Ahi*Blo.
// Weights pre-packed in MFMA B-frag order (hi/lo) once per call; activations
// stored as bf16 hi/lo row-major so A staging is a pure global_load_lds copy.

typedef __attribute__((ext_vector_type(8))) short     bf16x8;
typedef __attribute__((ext_vector_type(4))) float     f32x4;
typedef __attribute__((ext_vector_type(8))) unsigned short u16x8;

#define NGATE 5

__device__ __forceinline__ uint16_t f2bf(float f) {
    uint32_t u = __builtin_bit_cast(uint32_t, f);
    u = (u + 0x7fffu + ((u >> 16) & 1u)) >> 16;
    return (uint16_t)u;
}
__device__ __forceinline__ float bf2f(uint16_t h) {
    uint32_t u = ((uint32_t)h) << 16;
    return __builtin_bit_cast(float, u);
}
__device__ __forceinline__ float sigf(float x) { return 1.0f / (1.0f + __expf(-x)); }
__device__ __forceinline__ float tanhfast(float x) {
    float e = __expf(2.0f * x);          // bounded inputs (|x| < ~20) -> no inf
    return (e - 1.0f) / (e + 1.0f);
}

__device__ __forceinline__ void gld_lds16(const void* g, void* l) {
    __builtin_amdgcn_global_load_lds(
        (const __attribute__((address_space(1))) void*)g,
        (__attribute__((address_space(3))) void*)l,
        16, 0, 0);
}

// ---- pack weights into MFMA B-frag order, split hi/lo ----------------------
// dst[( nt*KT + kt )*64 + lane][j]  =  W[kt*32 + (lane>>4)*8 + j][nt*16 + (lane&15)]
// W rows: k<256 from W0, k>=256 from W1 (both row-major K x 1280).
__global__ __launch_bounds__(256) void pack_w_kernel(
    const float* __restrict__ W0, const float* __restrict__ W1, int KT,
    uint16_t* __restrict__ dhi, uint16_t* __restrict__ dlo)
{
    int gid = blockIdx.x * 256 + threadIdx.x;
    int total = 80 * KT * 64;
    if (gid >= total) return;
    int lane = gid & 63;
    int n  = ((gid >> 6) / KT) * 16 + (lane & 15);
    int kt = (gid >> 6) % KT;
    int k0 = kt * 32 + (lane >> 4) * 8;
    u16x8 vh, vl;
    #pragma unroll
    for (int j = 0; j < 8; ++j) {
        int k = k0 + j;
        const float* src = (k < 256) ? (W0 + (size_t)k * 1280)
                                     : (W1 + (size_t)(k - 256) * 1280);
        float v = src[n];
        uint16_t h = f2bf(v);
        vh[j] = h;
        vl[j] = f2bf(v - bf2f(h));
    }
    *(u16x8*)(dhi + (size_t)gid * 8) = vh;
    *(u16x8*)(dlo + (size_t)gid * 8) = vl;
}

// ---- fused level GEMM + LSTM cell ------------------------------------------
// Block: 256 thr = 4 waves. Tile: BM rows x 80 cols (5 gates x 16 dims).
// grid.y = jn in [0,16): output dims d = jn*16 + (lane&15).
// Wave w covers rows [w*BM/4, w*BM/4 + BM/4), MT = BM/64 mtiles of 16.
template<int BM, int KT, bool LVL0>
__global__ __launch_bounds__(256) void lvl_gemm(
    const uint16_t* __restrict__ Ahi, const uint16_t* __restrict__ Alo, // row-major, stride K
    const int* __restrict__ tokens, const float* __restrict__ emb,      // LVL0 only
    const uint16_t* __restrict__ Bhi, const uint16_t* __restrict__ Blo, // packed frag order
    const float* __restrict__ b,
    const float* __restrict__ c_prev,                                    // null for LVL0
    uint16_t* __restrict__ h_hi_out, uint16_t* __restrict__ h_lo_out,
    float* __restrict__ c_out, int n)
{
    constexpr int K   = KT * 32;
    constexpr int MT  = BM / 64;
    constexpr int ACH = BM / 16;   // 1KB A-chunks (16 rows x 32 k) per matrix

    __shared__ __align__(16) uint16_t lA[2][BM * 32];          // [hi/lo][row*32+k]
    __shared__ __align__(16) uint16_t lB[NGATE * 2 * 512];     // [g][hl][lane*8]

    const int tid  = threadIdx.x;
    const int wave = tid >> 6;
    const int lane = tid & 63;
    const int quad = lane >> 4;
    const int l15  = lane & 15;
    const int r0   = blockIdx.x * BM;
    const int jn   = blockIdx.y;

    f32x4 acc[MT][NGATE] = {};

    for (int kt = 0; kt < KT; ++kt) {
        // ---------------- stage A ----------------
        if (!LVL0) {
            for (int c = wave; c < 2 * ACH; c += 4) {
                int mat = (c >= ACH) ? 1 : 0;
                int ci  = mat ? (c - ACH) : c;
                const uint16_t* src = mat ? Alo : Ahi;
                int row = r0 + ci * 16 + (lane >> 2);
                row = min(row, n - 1);
                const uint16_t* g = src + (size_t)row * K + kt * 32 + (lane & 3) * 8;
                gld_lds16(g, &lA[mat][ci * 512]);   // HW: base + lane*16
            }
        } else {
            // gather emb[tokens] and split on the fly
            int row = tid >> 1, kh = tid & 1;
            int tok = tokens[r0 + row];
            const float* src = emb + (size_t)tok * 256 + kt * 32 + kh * 16;
            float v[16];
            #pragma unroll
            for (int q = 0; q < 4; ++q) {
                float4 f = *(const float4*)(src + 4 * q);
                v[4*q] = f.x; v[4*q+1] = f.y; v[4*q+2] = f.z; v[4*q+3] = f.w;
            }
            u16x8 h0, h1, l0, l1;
            #pragma unroll
            for (int j = 0; j < 8; ++j) {
                uint16_t h = f2bf(v[j]);     h0[j] = h; l0[j] = f2bf(v[j]     - bf2f(h));
                uint16_t g = f2bf(v[j + 8]); h1[j] = g; l1[j] = f2bf(v[j + 8] - bf2f(g));
            }
            int o = row * 32 + kh * 16;
            *(u16x8*)&lA[0][o]     = h0;  *(u16x8*)&lA[0][o + 8] = h1;
            *(u16x8*)&lA[1][o]     = l0;  *(u16x8*)&lA[1][o + 8] = l1;
        }
        // ---------------- stage B (packed -> pure copy) ----------------
        for (int c = wave; c < 2 * NGATE; c += 4) {
            int g  = c >> 1, hl = c & 1;
            const uint16_t* src = hl ? Blo : Bhi;
            int nt = g * 16 + jn;
            const uint16_t* gp = src + ((size_t)(nt * KT + kt) * 64 + lane) * 8;
            gld_lds16(gp, &lB[(g * 2 + hl) * 512]);
        }
        __syncthreads();

        // ---------------- MFMA ----------------
        bf16x8 a_hi[MT], a_lo[MT];
        #pragma unroll
        for (int mt = 0; mt < MT; ++mt) {
            int row = wave * (BM / 4) + mt * 16 + l15;
            a_hi[mt] = *(const bf16x8*)&lA[0][row * 32 + quad * 8];
            a_lo[mt] = *(const bf16x8*)&lA[1][row * 32 + quad * 8];
        }
        #pragma unroll
        for (int g = 0; g < NGATE; ++g) {
            bf16x8 bh = *(const bf16x8*)&lB[(g * 2 + 0) * 512 + lane * 8];
            bf16x8 bl = *(const bf16x8*)&lB[(g * 2 + 1) * 512 + lane * 8];
            #pragma unroll
            for (int mt = 0; mt < MT; ++mt) {
                acc[mt][g] = __builtin_amdgcn_mfma_f32_16x16x32_bf16(a_hi[mt], bh, acc[mt][g], 0, 0, 0);
                acc[mt][g] = __builtin_amdgcn_mfma_f32_16x16x32_bf16(a_lo[mt], bh, acc[mt][g], 0, 0, 0);
                acc[mt][g] = __builtin_amdgcn_mfma_f32_16x16x32_bf16(a_hi[mt], bl, acc[mt][g], 0, 0, 0);
            }
        }
        __syncthreads();
    }

    // ---------------- fused cell epilogue ----------------
    const int d = jn * 16 + l15;
    float bg[NGATE];
    #pragma unroll
    for (int g = 0; g < NGATE; ++g) bg[g] = b[g * 256 + d];

    #pragma unroll
    for (int mt = 0; mt < MT; ++mt) {
        int rb = r0 + wave * (BM / 4) + mt * 16 + quad * 4;
        #pragma unroll
        for (int v = 0; v < 4; ++v) {
            int row = rb + v;
            if (row < n) {
                float gi = acc[mt][0][v] + bg[0];
                float fl = acc[mt][1][v] + bg[1];
                float fr = acc[mt][2][v] + bg[2];
                float go = acc[mt][3][v] + bg[3];
                float gu = acc[mt][4][v] + bg[4];
                float cc;
                if (LVL0) {
                    cc = sigf(gi) * tanhfast(gu);
                } else {
                    float cl = c_prev[(size_t)(2 * row) * 256 + d];
                    float cr = c_prev[(size_t)(2 * row + 1) * 256 + d];
                    cc = sigf(gi) * tanhfast(gu) + sigf(fl) * cl + sigf(fr) * cr;
                }
                float hh = sigf(go) * tanhfast(cc);
                uint16_t hb = f2bf(hh);
                h_hi_out[(size_t)row * 256 + d] = hb;
                h_lo_out[(size_t)row * 256 + d] = f2bf(hh - bf2f(hb));
                c_out[(size_t)row * 256 + d] = cc;
            }
        }
    }
}

// ---- projection: out = hidden @ Wp + bp, hidden reconstructed hi+lo --------
__global__ __launch_bounds__(256) void proj_kernel(
    const uint16_t* __restrict__ h_hi, const uint16_t* __restrict__ h_lo,
    const float* __restrict__ Wp, const float* __restrict__ bp,
    float* __restrict__ out, int n)
{
    const int wave = blockIdx.x * 4 + (threadIdx.x >> 6);
    const int lane = threadIdx.x & 63;
    if (wave >= n) return;

    const uint16_t* hh = h_hi + (size_t)wave * 256;
    const uint16_t* hl = h_lo + (size_t)wave * 256;
    float s[5] = {0.f, 0.f, 0.f, 0.f, 0.f};
    #pragma unroll
    for (int q = 0; q < 4; ++q) {
        int dd = lane + 64 * q;
        float hv = bf2f(hh[dd]) + bf2f(hl[dd]);
        #pragma unroll
        for (int j = 0; j < 5; ++j) s[j] += hv * Wp[dd * 5 + j];
    }
    #pragma unroll
    for (int off = 32; off; off >>= 1)
        #pragma unroll
        for (int j = 0; j < 5; ++j) s[j] += __shfl_down(s[j], off);

    if (lane == 0) {
        #pragma unroll
        for (int j = 0; j < 5; ++j) out[(size_t)wave * 5 + j] = s[j] + bp[j];
    }
}

extern "C" void kernel_launch(void* const* d_in, const int* in_sizes, int n_in,
                              void* d_out, int out_size, void* d_ws, size_t ws_size,
                              hipStream_t stream)
{
    const int*   tokens = (const int*)  d_in[0];
    const float* emb    = (const float*)d_in[1];
    const float* Wx     = (const float*)d_in[2];
    const float* Ul     = (const float*)d_in[3];
    const float* Ur     = (const float*)d_in[4];
    const float* b      = (const float*)d_in[5];
    const float* Wp     = (const float*)d_in[6];
    const float* bp     = (const float*)d_in[7];
    float* out = (float*)d_out;

    // workspace carve (total ~62.6 MB)
    uint8_t* w = (uint8_t*)d_ws;
    uint16_t* h_hi = (uint16_t*)w;  w += (size_t)32767 * 256 * 2;
    uint16_t* h_lo = (uint16_t*)w;  w += (size_t)32767 * 256 * 2;
    float*    cA   = (float*)w;     w += (size_t)16384 * 256 * 4;
    float*    cB   = (float*)w;     w += (size_t)8192  * 256 * 4;
    uint16_t* BxH  = (uint16_t*)w;  w += (size_t)80 * 8  * 64 * 8 * 2;
    uint16_t* BxL  = (uint16_t*)w;  w += (size_t)80 * 8  * 64 * 8 * 2;
    uint16_t* BuH  = (uint16_t*)w;  w += (size_t)80 * 16 * 64 * 8 * 2;
    uint16_t* BuL  = (uint16_t*)w;  w += (size_t)80 * 16 * 64 * 8 * 2;

    pack_w_kernel<<<(80 * 8  * 64) / 256, 256, 0, stream>>>(Wx, Wx, 8,  BxH, BxL);
    pack_w_kernel<<<(80 * 16 * 64) / 256, 256, 0, stream>>>(Ul, Ur, 16, BuH, BuL);

    int off[16];
    off[0] = 0;
    for (int t = 0; t < 15; ++t) off[t + 1] = off[t] + (16384 >> t);

    // level 0
    lvl_gemm<128, 8, true><<<dim3(16384 / 128, 16), 256, 0, stream>>>(
        nullptr, nullptr, tokens, emb, BxH, BxL, b, nullptr,
        h_hi, h_lo, cA, 16384);

    // levels 1..14
    for (int t = 1; t <= 14; ++t) {
        int n = 16384 >> t;
        const uint16_t* Ah = h_hi + (size_t)off[t - 1] * 256;
        const uint16_t* Al = h_lo + (size_t)off[t - 1] * 256;
        float* c_in  = (t % 2 == 0) ? cB : cA;
        float* c_out = (t % 2 == 0) ? cA : cB;
        uint16_t* Hh = h_hi + (size_t)off[t] * 256;
        uint16_t* Hl = h_lo + (size_t)off[t] * 256;
        if (n >= 4096) {
            lvl_gemm<128, 16, false><<<dim3(n / 128, 16), 256, 0, stream>>>(
                Ah, Al, nullptr, nullptr, BuH, BuL, b, c_in, Hh, Hl, c_out, n);
        } else {
            int gx = (n + 63) / 64; if (gx < 1) gx = 1;
            lvl_gemm<64, 16, false><<<dim3(gx, 16), 256, 0, stream>>>(
                Ah, Al, nullptr, nullptr, BuH, BuL, b, c_in, Hh, Hl, c_out, n);
        }
    }

    int total = off[15];  // 32767
    proj_kernel<<<(total + 3) / 4, 256, 0, stream>>>(h_hi, h_lo, Wp, bp, out, total);
}